// Round 7
// baseline (815.653 us; speedup 1.0000x reference)
//
#include <hip/hip_runtime.h>
#include <hip/hip_bf16.h>

#define NN   50000
#define EE   1600000
#define FIN  128
#define FOUT 64
#define BETA  0.5f
#define ALPHA 0.2f
#define SBW    64           // src rows per bucket
#define SBSH   6            // log2(SBW)
#define NB     782          // ceil(NN/SBW)
#define RCAP   2504         // region capacity (mean 2046 + 10 sigma; 64B-aligned regions)
#define PGRID  512          // partition blocks: exactly 2 blocks/CU, balanced
#define PCHUNK 3125         // EE/PGRID exact
#define XS     136          // gemm X LDS stride (bf16 elems, 16B-aligned rows)
#define AS     68           // spmm acc stride in floats (68%32=4 -> bank spread)

typedef __attribute__((ext_vector_type(8))) short short8;
typedef __attribute__((ext_vector_type(8))) unsigned short ushort8v;
typedef __attribute__((ext_vector_type(4))) float float4v;

__device__ __forceinline__ float load_any(const void* p, long i, int isf32) {
    if (isf32) return ((const float*)p)[i];
    unsigned int b = ((unsigned int)(((const unsigned short*)p)[i])) << 16;
    return __uint_as_float(b);
}

__device__ __forceinline__ unsigned short f32_to_bf16_rne(float f) {
    unsigned int b = __float_as_uint(f);
    return (unsigned short)((b + 0x7FFF + ((b >> 16) & 1)) >> 16);
}

__device__ __forceinline__ float bf16_to_f32(unsigned short u) {
    return __uint_as_float(((unsigned int)u) << 16);
}

// ---------------------------------------------------------------------------
// Kernel 0: fused detect(W,Mv) + W transpose -> Wt bf16 [64][128] + bcur zero.
// ---------------------------------------------------------------------------
__global__ __launch_bounds__(256) void detwt_kernel(
    const void* __restrict__ W, const void* __restrict__ Mv,
    unsigned short* __restrict__ Wt, int* __restrict__ flags,
    int* __restrict__ bcur)
{
    __shared__ int vote;
    const int tid = threadIdx.x;
    if (tid == 0) vote = 0;
    __syncthreads();

    int m = 0;
    const float vw = bf16_to_f32(((const unsigned short*)W)[tid * 16]);
    if (isnan(vw) || fabsf(vw) > 1e4f) m |= 1;
    if (blockIdx.x == 0) {
        const long half = (long)EE >> 1;
        const long pos = 2 * (((long)tid * (half / 256)) % half);
        const float vm = bf16_to_f32(((const unsigned short*)Mv)[pos]);
        if (isnan(vm) || fabsf(vm) > 1e4f) m |= 2;
    }
    if (m) atomicOr(&vote, m);
    __syncthreads();

    const int fW = vote & 1;
    if (blockIdx.x == 0) {
        if (tid == 0) flags[1] = (vote >> 1) & 1;
        for (int i = tid; i < NB; i += 256) bcur[i] = 0;
    }
    const int i = blockIdx.x * 256 + tid;          // grid = 32 blocks, i < 8192
    const int k = i >> 6, n = i & 63;              // read W coalesced
    Wt[n * FIN + k] = f32_to_bf16_rne(load_any(W, i, fW));
}

// ---------------------------------------------------------------------------
// Kernel 1: MFMA gemm (R6-validated). 2 tiles (32 rows) per block, grid 1563.
// X staged via one 16 B vector load/thread; B-fragments direct from global Wt.
// ---------------------------------------------------------------------------
__global__ __launch_bounds__(256) void mfma_gemm_kernel(
    const void* __restrict__ inp,
    const unsigned short* __restrict__ Wt,   // bf16 [64][128]
    const void* __restrict__ a,
    unsigned short* __restrict__ h,
    float* __restrict__ s1,
    float* __restrict__ s2,
    int* __restrict__ flags)
{
    __shared__ unsigned short Xs[16 * XS];   // 4.25 KB
    __shared__ float part1[4][16];
    __shared__ float part2[4][16];
    __shared__ int vote;

    const int tid  = threadIdx.x;
    const int wave = tid >> 6;
    const int lane = tid & 63;
    const int quad = lane >> 4;
    const int col  = lane & 15;
    const int rb0  = blockIdx.x * 32;

    if (tid == 0) vote = 0;
    __syncthreads();

    {   // dtype probes over this block's own rows (in-bounds for bf16 size)
        int m = 0;
        const float vi = bf16_to_f32(((const unsigned short*)inp)[(long)rb0 * FIN + tid * 8]);
        if (isnan(vi) || fabsf(vi) > 1e4f) m |= 1;                    // fI
        if (tid < 128) {
            const float va = bf16_to_f32(((const unsigned short*)a)[tid]);
            if (isnan(va) || fabsf(va) > 1e4f) m |= 2;                // fA
        }
        if (m) atomicOr(&vote, m);
    }
    __syncthreads();
    const int fI = vote & 1, fA = (vote >> 1) & 1;
    if (blockIdx.x == 0 && tid == 0) flags[0] = fI;

    const int nb = wave * 16;
    const float a1 = load_any(a, nb + col, fA);
    const float a2 = load_any(a, 64 + nb + col, fA);

    for (int t = 0; t < 2; ++t) {
        const int rb = rb0 + t * 16;
        if (rb >= NN) break;             // block-uniform (rb0 uniform)

        {   // stage X -> LDS bf16
            const int r = tid >> 4, k8 = (tid & 15) * 8;
            if (!fI) {
                const unsigned short* src = (const unsigned short*)inp + (long)(rb + r) * FIN + k8;
                *(ushort8v*)&Xs[r * XS + k8] = *(const ushort8v*)src;
            } else {
                const float* src = (const float*)inp + (long)(rb + r) * FIN + k8;
                ushort8v v;
                #pragma unroll
                for (int j = 0; j < 8; ++j) v[j] = f32_to_bf16_rne(src[j]);
                *(ushort8v*)&Xs[r * XS + k8] = v;
            }
        }
        __syncthreads();

        float4v acc = { 0.f, 0.f, 0.f, 0.f };
        #pragma unroll
        for (int k0 = 0; k0 < FIN; k0 += 32) {
            const short8 af = *(const short8*)&Xs[col * XS + k0 + quad * 8];
            const short8 bf = *(const short8*)&Wt[(long)(nb + col) * FIN + k0 + quad * 8];
            acc = __builtin_amdgcn_mfma_f32_16x16x32_bf16(af, bf, acc, 0, 0, 0);
        }

        #pragma unroll
        for (int r = 0; r < 4; ++r)
            h[(long)(rb + quad * 4 + r) * FOUT + nb + col] = f32_to_bf16_rne(acc[r]);

        #pragma unroll
        for (int r = 0; r < 4; ++r) {
            float v1 = acc[r] * a1;
            float v2 = acc[r] * a2;
            #pragma unroll
            for (int o = 1; o < 16; o <<= 1) {
                v1 += __shfl_xor(v1, o, 64);
                v2 += __shfl_xor(v2, o, 64);
            }
            if (col == 0) {
                part1[wave][quad * 4 + r] = v1;
                part2[wave][quad * 4 + r] = v2;
            }
        }
        __syncthreads();
        if (tid < 16) {
            s1[rb + tid] = part1[0][tid] + part1[1][tid] + part1[2][tid] + part1[3][tid];
            s2[rb + tid] = part2[0][tid] + part2[1][tid] + part2[2][tid] + part2[3][tid];
        }
        // next iteration's staging barrier orders Xs/part reuse.
    }
}

// ---------------------------------------------------------------------------
// Kernel 2: partition into 782 buckets with FIXED regions (b*RCAP).
// PGRID=512 (PCHUNK=3125): exactly 2 blocks/CU, balanced, 32 waves/CU.
// Record: src<<32 | dst<<16 | bf16(edge_e). LDS-ranked contiguous run writes
// (R5 lesson: raw 4B scatter = 99 MB HBM writes, 120 us).
// ---------------------------------------------------------------------------
__global__ __launch_bounds__(1024) void partition_kernel(
    const int* __restrict__ edge,
    const void* __restrict__ Mv,
    const int* __restrict__ flags,
    const float* __restrict__ s1,
    const float* __restrict__ s2,
    int* __restrict__ bcur,              // [NB], zeroed; per-bucket count
    unsigned long long* __restrict__ recs)
{
    __shared__ int lcnt[NB];
    __shared__ int lbase[NB];
    const int tid = threadIdx.x;
    const int fM = flags[1];
    const int e0 = blockIdx.x * PCHUNK;

    if (tid < NB) lcnt[tid] = 0;
    __syncthreads();

    int srcs[4], dsts[4];
    float mvs[4];
    #pragma unroll
    for (int k = 0; k < 4; ++k) {
        const int e = e0 + tid + 1024 * k;
        const bool ok = (tid + 1024 * k) < PCHUNK;
        srcs[k] = ok ? edge[e] : -1;
        dsts[k] = ok ? edge[EE + e] : 0;
        mvs[k]  = ok ? load_any(Mv, e, fM) : 0.f;
    }
    #pragma unroll
    for (int k = 0; k < 4; ++k)
        if (srcs[k] >= 0) atomicAdd(&lcnt[srcs[k] >> SBSH], 1);
    __syncthreads();

    if (tid < NB) {
        const int c = lcnt[tid];
        const int o = c ? atomicAdd(&bcur[tid], c) : 0;
        lbase[tid] = tid * RCAP + o;
        lcnt[tid] = 0;                 // reuse as rank counter
    }
    __syncthreads();

    float ss1[4], ss2[4];
    #pragma unroll
    for (int k = 0; k < 4; ++k) {
        ss1[k] = (srcs[k] >= 0) ? s1[srcs[k]] : 0.f;
        ss2[k] = (srcs[k] >= 0) ? s2[dsts[k]] : 0.f;
    }
    #pragma unroll
    for (int k = 0; k < 4; ++k) {
        if (srcs[k] < 0) continue;
        const float bias = mvs[k] * BETA + (1.f - BETA);
        const float x  = ss1[k] + bias * ss2[k];
        const float lr = x > 0.f ? x : ALPHA * x;
        const float ee = __expf(lr);
        const int b = srcs[k] >> SBSH;
        const int r = atomicAdd(&lcnt[b], 1);
        const int pos = lbase[b] + r;
        if (pos < (b + 1) * RCAP)      // graceful guard (P ~ 1e-22)
            recs[pos] = ((unsigned long long)(unsigned)srcs[k] << 32)
                      | ((unsigned long long)(unsigned)dsts[k] << 16)
                      | (unsigned long long)f32_to_bf16_rne(ee);
    }
}

// ---------------------------------------------------------------------------
// Kernel 3: LDS-accumulator SpMM (R7). No CSR phases, no divergence:
// 17 KB f32 acc tile [64 rows][68] per bucket; edge-parallel uniform loop
// (8-lane group per edge: 64 B coalesced rec reads/wave, 16 B h-gather/lane,
// 8x ds_add_f32 into acc + masked rsum add). Stride 68 spreads banks
// (<=2-way ~ free). Finalize: 512 threads cover 64 rows x 8 slices.
// ---------------------------------------------------------------------------
__global__ __launch_bounds__(512) void spmm_kernel(
    const int* __restrict__ bcur,
    const unsigned long long* __restrict__ recs,
    const unsigned short* __restrict__ h,   // bf16 [NN, FOUT]
    const int* __restrict__ flags,
    void* __restrict__ out)
{
    __shared__ float acc[SBW][AS];          // 17 KB
    __shared__ float lrsum[SBW];
    const int b   = blockIdx.x;
    const int tid = threadIdx.x;
    const int grp = tid >> 3;               // 0..63: edge slot / finalize row
    const int sl  = tid & 7;                // features 8*sl .. 8*sl+7
    const int rb  = b * SBW;
    const int beg = b * RCAP;

    int n = bcur[b]; if (n > RCAP) n = RCAP;

    for (int i = tid; i < SBW * AS; i += 512) (&acc[0][0])[i] = 0.f;
    if (tid < SBW) lrsum[tid] = 0.f;
    __syncthreads();

    const int f0 = 8 * sl;
    int j = grp;
    for (; j + 192 < n; j += 256) {          // 4 edges in flight per group
        unsigned long long r4[4];
        #pragma unroll
        for (int k = 0; k < 4; ++k) r4[k] = recs[beg + j + 64 * k];
        ushort8v hv[4];
        #pragma unroll
        for (int k = 0; k < 4; ++k)
            hv[k] = *(const ushort8v*)&h[(long)((unsigned)(r4[k] >> 16) & 0xFFFFu) * FOUT + f0];
        #pragma unroll
        for (int k = 0; k < 4; ++k) {
            const int r = (int)(r4[k] >> 32) - rb;
            const float v = bf16_to_f32((unsigned short)(r4[k] & 0xFFFFu));
            float* a = &acc[r][f0];
            atomicAdd(&a[0], v * bf16_to_f32(hv[k][0]));
            atomicAdd(&a[1], v * bf16_to_f32(hv[k][1]));
            atomicAdd(&a[2], v * bf16_to_f32(hv[k][2]));
            atomicAdd(&a[3], v * bf16_to_f32(hv[k][3]));
            atomicAdd(&a[4], v * bf16_to_f32(hv[k][4]));
            atomicAdd(&a[5], v * bf16_to_f32(hv[k][5]));
            atomicAdd(&a[6], v * bf16_to_f32(hv[k][6]));
            atomicAdd(&a[7], v * bf16_to_f32(hv[k][7]));
            if (sl == 0) atomicAdd(&lrsum[r], v);
        }
    }
    for (; j < n; j += 64) {                 // tail (uniform across block? no:
        // per-group bound -> groups drop out; no barriers inside -> safe)
        const unsigned long long rec = recs[beg + j];
        const int r = (int)(rec >> 32) - rb;
        const float v = bf16_to_f32((unsigned short)(rec & 0xFFFFu));
        const ushort8v hv = *(const ushort8v*)&h[(long)((unsigned)(rec >> 16) & 0xFFFFu) * FOUT + f0];
        float* a = &acc[r][f0];
        atomicAdd(&a[0], v * bf16_to_f32(hv[0]));
        atomicAdd(&a[1], v * bf16_to_f32(hv[1]));
        atomicAdd(&a[2], v * bf16_to_f32(hv[2]));
        atomicAdd(&a[3], v * bf16_to_f32(hv[3]));
        atomicAdd(&a[4], v * bf16_to_f32(hv[4]));
        atomicAdd(&a[5], v * bf16_to_f32(hv[5]));
        atomicAdd(&a[6], v * bf16_to_f32(hv[6]));
        atomicAdd(&a[7], v * bf16_to_f32(hv[7]));
        if (sl == 0) atomicAdd(&lrsum[r], v);
    }
    __syncthreads();

    // ---- finalize: thread (grp, sl) -> row rb+grp, features f0..f0+7 ----
    const int row = rb + grp;
    if (row >= NN) return;
    const float rs = lrsum[grp];
    const int fOut = flags[0];
    float q[8];
    if (rs != 0.f) {
        const float inv = 1.f / rs;
        #pragma unroll
        for (int i = 0; i < 8; ++i) {
            float x = acc[grp][f0 + i] * inv;
            q[i] = x > 0.f ? x : (__expf(x) - 1.f);
        }
    } else {
        #pragma unroll
        for (int i = 0; i < 8; ++i) q[i] = 0.f;
    }
    if (fOut) {
        float4* o = (float4*)((float*)out + (long)row * FOUT + f0);
        o[0] = make_float4(q[0], q[1], q[2], q[3]);
        o[1] = make_float4(q[4], q[5], q[6], q[7]);
    } else {
        ushort8v ov;
        #pragma unroll
        for (int i = 0; i < 8; ++i) ov[i] = f32_to_bf16_rne(q[i]);
        *(ushort8v*)((unsigned short*)out + (long)row * FOUT + f0) = ov;
    }
}

extern "C" void kernel_launch(void* const* d_in, const int* in_sizes, int n_in,
                              void* d_out, int out_size, void* d_ws, size_t ws_size,
                              hipStream_t stream) {
    const void* inp  = d_in[0];
    const void* Mv   = d_in[1];
    const void* W    = d_in[2];
    const void* a    = d_in[3];
    const int*  edge = (const int*)d_in[4];

    // ws: flags | Wt bf16[64*128] | h bf16[NN*64] | s1[NN] | s2[NN] | bcur[NB] | recs u64[NB*RCAP]
    char* p = (char*)d_ws;
    int*                flags  = (int*)p;            p += 256;
    unsigned short*     Wt     = (unsigned short*)p; p += ((size_t)FOUT * FIN * 2 + 255) / 256 * 256;
    unsigned short*     h      = (unsigned short*)p; p += ((size_t)NN * FOUT * 2 + 255) / 256 * 256;
    float*              s1     = (float*)p;          p += ((size_t)NN * 4 + 255) / 256 * 256;
    float*              s2     = (float*)p;          p += ((size_t)NN * 4 + 255) / 256 * 256;
    int*                bcur   = (int*)p;            p += ((size_t)NB * 4 + 255) / 256 * 256;
    unsigned long long* recs   = (unsigned long long*)p;

    detwt_kernel<<<32, 256, 0, stream>>>(W, Mv, Wt, flags, bcur);
    mfma_gemm_kernel<<<(NN + 31) / 32, 256, 0, stream>>>(inp, Wt, a, h, s1, s2, flags);
    partition_kernel<<<PGRID, 1024, 0, stream>>>(edge, Mv, flags, s1, s2, bcur, recs);
    spmm_kernel<<<NB, 512, 0, stream>>>(bcur, recs, h, flags, d_out);
}

// Round 8
// 154.448 us; speedup vs baseline: 5.2811x; 5.2811x over previous
//
#include <hip/hip_runtime.h>
#include <hip/hip_bf16.h>

#define NN   50000
#define EE   1600000
#define FIN  128
#define FOUT 64
#define BETA  0.5f
#define ALPHA 0.2f
#define SBW    64           // src rows per bucket (4 blocks/CU in csr_spmm)
#define SBSH   6            // log2(SBW)
#define NB     782          // ceil(NN/SBW)
#define RCAP   2500         // region capacity (mean 2046 + 10 sigma)
#define PGRID  512          // partition blocks: exactly 2 blocks/CU, balanced
#define PCHUNK 3125         // EE/PGRID exact
#define CAPB   2504         // LDS record cache (covers RCAP)
#define XS     136          // gemm X LDS stride (bf16 elems, 16B-aligned rows)

typedef __attribute__((ext_vector_type(8))) short short8;
typedef __attribute__((ext_vector_type(8))) unsigned short ushort8v;
typedef __attribute__((ext_vector_type(4))) float float4v;

__device__ __forceinline__ float load_any(const void* p, long i, int isf32) {
    if (isf32) return ((const float*)p)[i];
    unsigned int b = ((unsigned int)(((const unsigned short*)p)[i])) << 16;
    return __uint_as_float(b);
}

__device__ __forceinline__ unsigned short f32_to_bf16_rne(float f) {
    unsigned int b = __float_as_uint(f);
    return (unsigned short)((b + 0x7FFF + ((b >> 16) & 1)) >> 16);
}

__device__ __forceinline__ float bf16_to_f32(unsigned short u) {
    return __uint_as_float(((unsigned int)u) << 16);
}

// ---------------------------------------------------------------------------
// Kernel 0: fused detect(W,Mv) + W transpose -> Wt bf16 [64][128] + bcur zero.
// ---------------------------------------------------------------------------
__global__ __launch_bounds__(256) void detwt_kernel(
    const void* __restrict__ W, const void* __restrict__ Mv,
    unsigned short* __restrict__ Wt, int* __restrict__ flags,
    int* __restrict__ bcur)
{
    __shared__ int vote;
    const int tid = threadIdx.x;
    if (tid == 0) vote = 0;
    __syncthreads();

    int m = 0;
    const float vw = bf16_to_f32(((const unsigned short*)W)[tid * 16]);
    if (isnan(vw) || fabsf(vw) > 1e4f) m |= 1;
    if (blockIdx.x == 0) {
        const long half = (long)EE >> 1;
        const long pos = 2 * (((long)tid * (half / 256)) % half);
        const float vm = bf16_to_f32(((const unsigned short*)Mv)[pos]);
        if (isnan(vm) || fabsf(vm) > 1e4f) m |= 2;
    }
    if (m) atomicOr(&vote, m);
    __syncthreads();

    const int fW = vote & 1;
    if (blockIdx.x == 0) {
        if (tid == 0) flags[1] = (vote >> 1) & 1;
        for (int i = tid; i < NB; i += 256) bcur[i] = 0;
    }
    const int i = blockIdx.x * 256 + tid;          // grid = 32 blocks, i < 8192
    const int k = i >> 6, n = i & 63;              // read W coalesced
    Wt[n * FIN + k] = f32_to_bf16_rne(load_any(W, i, fW));
}

// ---------------------------------------------------------------------------
// Kernel 1: MFMA gemm (R6-validated). 2 tiles (32 rows) per block, grid 1563.
// X staged via one 16 B vector load/thread; B-fragments direct from global Wt.
// ---------------------------------------------------------------------------
__global__ __launch_bounds__(256) void mfma_gemm_kernel(
    const void* __restrict__ inp,
    const unsigned short* __restrict__ Wt,   // bf16 [64][128]
    const void* __restrict__ a,
    unsigned short* __restrict__ h,
    float* __restrict__ s1,
    float* __restrict__ s2,
    int* __restrict__ flags)
{
    __shared__ unsigned short Xs[16 * XS];   // 4.25 KB
    __shared__ float part1[4][16];
    __shared__ float part2[4][16];
    __shared__ int vote;

    const int tid  = threadIdx.x;
    const int wave = tid >> 6;
    const int lane = tid & 63;
    const int quad = lane >> 4;
    const int col  = lane & 15;
    const int rb0  = blockIdx.x * 32;

    if (tid == 0) vote = 0;
    __syncthreads();

    {   // dtype probes over this block's own rows (in-bounds for bf16 size)
        int m = 0;
        const float vi = bf16_to_f32(((const unsigned short*)inp)[(long)rb0 * FIN + tid * 8]);
        if (isnan(vi) || fabsf(vi) > 1e4f) m |= 1;                    // fI
        if (tid < 128) {
            const float va = bf16_to_f32(((const unsigned short*)a)[tid]);
            if (isnan(va) || fabsf(va) > 1e4f) m |= 2;                // fA
        }
        if (m) atomicOr(&vote, m);
    }
    __syncthreads();
    const int fI = vote & 1, fA = (vote >> 1) & 1;
    if (blockIdx.x == 0 && tid == 0) flags[0] = fI;

    const int nb = wave * 16;
    const float a1 = load_any(a, nb + col, fA);
    const float a2 = load_any(a, 64 + nb + col, fA);

    for (int t = 0; t < 2; ++t) {
        const int rb = rb0 + t * 16;
        if (rb >= NN) break;             // block-uniform (rb0 uniform)

        {   // stage X -> LDS bf16
            const int r = tid >> 4, k8 = (tid & 15) * 8;
            if (!fI) {
                const unsigned short* src = (const unsigned short*)inp + (long)(rb + r) * FIN + k8;
                *(ushort8v*)&Xs[r * XS + k8] = *(const ushort8v*)src;
            } else {
                const float* src = (const float*)inp + (long)(rb + r) * FIN + k8;
                ushort8v v;
                #pragma unroll
                for (int j = 0; j < 8; ++j) v[j] = f32_to_bf16_rne(src[j]);
                *(ushort8v*)&Xs[r * XS + k8] = v;
            }
        }
        __syncthreads();

        float4v acc = { 0.f, 0.f, 0.f, 0.f };
        #pragma unroll
        for (int k0 = 0; k0 < FIN; k0 += 32) {
            const short8 af = *(const short8*)&Xs[col * XS + k0 + quad * 8];
            const short8 bf = *(const short8*)&Wt[(long)(nb + col) * FIN + k0 + quad * 8];
            acc = __builtin_amdgcn_mfma_f32_16x16x32_bf16(af, bf, acc, 0, 0, 0);
        }

        #pragma unroll
        for (int r = 0; r < 4; ++r)
            h[(long)(rb + quad * 4 + r) * FOUT + nb + col] = f32_to_bf16_rne(acc[r]);

        #pragma unroll
        for (int r = 0; r < 4; ++r) {
            float v1 = acc[r] * a1;
            float v2 = acc[r] * a2;
            #pragma unroll
            for (int o = 1; o < 16; o <<= 1) {
                v1 += __shfl_xor(v1, o, 64);
                v2 += __shfl_xor(v2, o, 64);
            }
            if (col == 0) {
                part1[wave][quad * 4 + r] = v1;
                part2[wave][quad * 4 + r] = v2;
            }
        }
        __syncthreads();
        if (tid < 16) {
            s1[rb + tid] = part1[0][tid] + part1[1][tid] + part1[2][tid] + part1[3][tid];
            s2[rb + tid] = part2[0][tid] + part2[1][tid] + part2[2][tid] + part2[3][tid];
        }
        // next iteration's staging barrier orders Xs/part reuse.
    }
}

// ---------------------------------------------------------------------------
// Kernel 2: partition into 782 buckets with FIXED regions (b*RCAP).
// R8: s1/s2 gathers issued IMMEDIATELY after the edge loads (they are the
// longest-latency ops; previously issued after both barriers, latency naked
// on the critical path; compiler cannot hoist loads across __syncthreads).
// Their ~300-500cy now hides under the LDS count phase + 2 barriers + scan.
// Record: src<<32 | dst<<16 | bf16(edge_e). LDS-ranked contiguous run writes
// (R5 lesson: raw 4B scatter = 99 MB HBM writes, 120 us).
// ---------------------------------------------------------------------------
__global__ __launch_bounds__(1024) void partition_kernel(
    const int* __restrict__ edge,
    const void* __restrict__ Mv,
    const int* __restrict__ flags,
    const float* __restrict__ s1,
    const float* __restrict__ s2,
    int* __restrict__ bcur,              // [NB], zeroed; per-bucket count
    unsigned long long* __restrict__ recs)
{
    __shared__ int lcnt[NB];
    __shared__ int lbase[NB];
    const int tid = threadIdx.x;
    const int fM = flags[1];
    const int e0 = blockIdx.x * PCHUNK;

    if (tid < NB) lcnt[tid] = 0;
    __syncthreads();

    int srcs[4], dsts[4];
    #pragma unroll
    for (int k = 0; k < 4; ++k) {
        const int e = e0 + tid + 1024 * k;
        const bool ok = (tid + 1024 * k) < PCHUNK;
        srcs[k] = ok ? edge[e] : -1;
        dsts[k] = ok ? edge[EE + e] : 0;
    }

    // issue the random gathers + Mv stream NOW: latency overlaps the count
    // phase, both barriers, and the scan below.
    float ss1[4], ss2[4], mvs[4];
    #pragma unroll
    for (int k = 0; k < 4; ++k) {
        ss1[k] = (srcs[k] >= 0) ? s1[srcs[k]] : 0.f;
        ss2[k] = (srcs[k] >= 0) ? s2[dsts[k]] : 0.f;
    }
    #pragma unroll
    for (int k = 0; k < 4; ++k) {
        const int e = e0 + tid + 1024 * k;
        mvs[k] = ((tid + 1024 * k) < PCHUNK) ? load_any(Mv, e, fM) : 0.f;
    }

    #pragma unroll
    for (int k = 0; k < 4; ++k)
        if (srcs[k] >= 0) atomicAdd(&lcnt[srcs[k] >> SBSH], 1);
    __syncthreads();

    if (tid < NB) {
        const int c = lcnt[tid];
        const int o = c ? atomicAdd(&bcur[tid], c) : 0;
        lbase[tid] = tid * RCAP + o;
        lcnt[tid] = 0;                 // reuse as rank counter
    }
    __syncthreads();

    #pragma unroll
    for (int k = 0; k < 4; ++k) {
        if (srcs[k] < 0) continue;
        const float bias = mvs[k] * BETA + (1.f - BETA);
        const float x  = ss1[k] + bias * ss2[k];
        const float lr = x > 0.f ? x : ALPHA * x;
        const float ee = __expf(lr);
        const int b = srcs[k] >> SBSH;
        const int r = atomicAdd(&lcnt[b], 1);
        const int pos = lbase[b] + r;
        if (pos < (b + 1) * RCAP)      // graceful guard (P ~ 1e-22)
            recs[pos] = ((unsigned long long)(unsigned)srcs[k] << 32)
                      | ((unsigned long long)(unsigned)dsts[k] << 16)
                      | (unsigned long long)f32_to_bf16_rne(ee);
    }
}

// ---------------------------------------------------------------------------
// Kernel 3: fused CSR finalize + SpMM + finalize (R4/R6-validated).
// SBW=64 buckets, 512-thread blocks, ~31 KB LDS -> 4 blocks/CU, 32 waves/CU.
// SpMM: each 8-lane group owns one row (lane = 8-feature slice); lpair reads
// broadcast within the group; no cross-lane reduction; unroll-4 (VGPR 52 ->
// keeps 8 waves/SIMD). R7 lesson: LDS f32 atomicAdd = CAS loop, 14x slower —
// the grouping passes here are the right design.
// ---------------------------------------------------------------------------
__global__ __launch_bounds__(512) void csr_spmm_kernel(
    const int* __restrict__ bcur,
    const unsigned long long* __restrict__ recs,
    const unsigned short* __restrict__ h,   // bf16 [NN, FOUT]
    const int* __restrict__ flags,
    void* __restrict__ out)
{
    __shared__ unsigned long long lrec[CAPB];   // 20 KB
    __shared__ unsigned int lpair[CAPB];        // 10 KB
    __shared__ int cnt[SBW];
    __shared__ int off[SBW];
    const int b    = blockIdx.x;
    const int tid  = threadIdx.x;
    const int rb   = b * SBW;
    const int beg  = b * RCAP;

    int n = bcur[b]; if (n > RCAP) n = RCAP;

    if (tid < SBW) cnt[tid] = 0;
    __syncthreads();

    // pass 1: load + count + rank; repack hi32 = r | rank<<8 (r<64, rank<2^12)
    for (int j = tid; j < n; j += 512) {
        const unsigned long long rec = recs[beg + j];
        const int r = (int)(rec >> 32) - rb;
        const int rank = atomicAdd(&cnt[r], 1);
        lrec[j] = ((unsigned long long)(unsigned)(r | (rank << 8)) << 32)
                | (unsigned long long)(unsigned)(rec & 0xFFFFFFFFu);
    }
    __syncthreads();

    // exclusive scan of the 64 counters by wave 0 (cnt preserved = row length)
    if (tid < SBW) {
        const int c = cnt[tid];
        int x = c;
        #pragma unroll
        for (int o = 1; o < SBW; o <<= 1) {
            int y = __shfl_up(x, o, 64);
            if (tid >= o) x += y;
        }
        off[tid] = x - c;
    }
    __syncthreads();

    // pass 2: atomic-free scatter into row-grouped lpair
    for (int j = tid; j < n; j += 512) {
        const unsigned long long rec = lrec[j];
        const unsigned int hi = (unsigned int)(rec >> 32);
        lpair[off[hi & 63u] + (hi >> 8)] = (unsigned int)(rec & 0xFFFFFFFFu);
    }
    __syncthreads();

    // ---- SpMM: 8 waves x 8 groups; group (wv,gr) owns row rb + wv*8 + gr ----
    const int wv   = tid >> 6;
    const int lane = tid & 63;
    const int gr   = lane >> 3;          // row-group within wave
    const int sl   = lane & 7;           // features 8*sl .. 8*sl+7
    const int rr   = wv * 8 + gr;        // 0..63
    const int row  = rb + rr;
    const int fOut = flags[0];

    const int jb = off[rr];
    const int je = jb + cnt[rr];

    float acc0 = 0.f, acc1 = 0.f, acc2 = 0.f, acc3 = 0.f;
    float acc4 = 0.f, acc5 = 0.f, acc6 = 0.f, acc7 = 0.f;
    float rsum = 0.f;
    int j = jb;
    for (; j + 3 < je; j += 4) {         // 4 gathers in flight per lane
        unsigned int u[4];
        #pragma unroll
        for (int kk = 0; kk < 4; ++kk) u[kk] = lpair[j + kk];   // group-broadcast
        ushort8v hv[4];
        #pragma unroll
        for (int kk = 0; kk < 4; ++kk)
            hv[kk] = *(const ushort8v*)&h[(long)(u[kk] >> 16) * FOUT + 8 * sl];
        #pragma unroll
        for (int kk = 0; kk < 4; ++kk) {
            const float v = bf16_to_f32((unsigned short)(u[kk] & 0xFFFFu));
            rsum += v;
            acc0 = fmaf(v, bf16_to_f32(hv[kk][0]), acc0);
            acc1 = fmaf(v, bf16_to_f32(hv[kk][1]), acc1);
            acc2 = fmaf(v, bf16_to_f32(hv[kk][2]), acc2);
            acc3 = fmaf(v, bf16_to_f32(hv[kk][3]), acc3);
            acc4 = fmaf(v, bf16_to_f32(hv[kk][4]), acc4);
            acc5 = fmaf(v, bf16_to_f32(hv[kk][5]), acc5);
            acc6 = fmaf(v, bf16_to_f32(hv[kk][6]), acc6);
            acc7 = fmaf(v, bf16_to_f32(hv[kk][7]), acc7);
        }
    }
    for (; j < je; ++j) {                // tail
        const unsigned int u = lpair[j];
        const ushort8v hv = *(const ushort8v*)&h[(long)(u >> 16) * FOUT + 8 * sl];
        const float v = bf16_to_f32((unsigned short)(u & 0xFFFFu));
        rsum += v;
        acc0 = fmaf(v, bf16_to_f32(hv[0]), acc0);
        acc1 = fmaf(v, bf16_to_f32(hv[1]), acc1);
        acc2 = fmaf(v, bf16_to_f32(hv[2]), acc2);
        acc3 = fmaf(v, bf16_to_f32(hv[3]), acc3);
        acc4 = fmaf(v, bf16_to_f32(hv[4]), acc4);
        acc5 = fmaf(v, bf16_to_f32(hv[5]), acc5);
        acc6 = fmaf(v, bf16_to_f32(hv[6]), acc6);
        acc7 = fmaf(v, bf16_to_f32(hv[7]), acc7);
    }

    if (row < NN && je > jb) {
        const float inv = 1.f / rsum;    // identical across the 8 lanes
        float q0 = acc0 * inv, q1 = acc1 * inv, q2 = acc2 * inv, q3 = acc3 * inv;
        float q4 = acc4 * inv, q5 = acc5 * inv, q6 = acc6 * inv, q7 = acc7 * inv;
        q0 = q0 > 0.f ? q0 : (__expf(q0) - 1.f);
        q1 = q1 > 0.f ? q1 : (__expf(q1) - 1.f);
        q2 = q2 > 0.f ? q2 : (__expf(q2) - 1.f);
        q3 = q3 > 0.f ? q3 : (__expf(q3) - 1.f);
        q4 = q4 > 0.f ? q4 : (__expf(q4) - 1.f);
        q5 = q5 > 0.f ? q5 : (__expf(q5) - 1.f);
        q6 = q6 > 0.f ? q6 : (__expf(q6) - 1.f);
        q7 = q7 > 0.f ? q7 : (__expf(q7) - 1.f);
        if (fOut) {
            float4* o = (float4*)((float*)out + (long)row * FOUT + 8 * sl);
            o[0] = make_float4(q0, q1, q2, q3);
            o[1] = make_float4(q4, q5, q6, q7);
        } else {
            ushort8v ov;
            ov[0] = f32_to_bf16_rne(q0); ov[1] = f32_to_bf16_rne(q1);
            ov[2] = f32_to_bf16_rne(q2); ov[3] = f32_to_bf16_rne(q3);
            ov[4] = f32_to_bf16_rne(q4); ov[5] = f32_to_bf16_rne(q5);
            ov[6] = f32_to_bf16_rne(q6); ov[7] = f32_to_bf16_rne(q7);
            *(ushort8v*)((unsigned short*)out + (long)row * FOUT + 8 * sl) = ov;
        }
    } else if (row < NN) {               // empty row: emit zeros
        if (fOut) {
            float4* o = (float4*)((float*)out + (long)row * FOUT + 8 * sl);
            o[0] = make_float4(0.f, 0.f, 0.f, 0.f);
            o[1] = make_float4(0.f, 0.f, 0.f, 0.f);
        } else {
            ushort8v ov = { 0, 0, 0, 0, 0, 0, 0, 0 };
            *(ushort8v*)((unsigned short*)out + (long)row * FOUT + 8 * sl) = ov;
        }
    }
}

extern "C" void kernel_launch(void* const* d_in, const int* in_sizes, int n_in,
                              void* d_out, int out_size, void* d_ws, size_t ws_size,
                              hipStream_t stream) {
    const void* inp  = d_in[0];
    const void* Mv   = d_in[1];
    const void* W    = d_in[2];
    const void* a    = d_in[3];
    const int*  edge = (const int*)d_in[4];

    // ws: flags | Wt bf16[64*128] | h bf16[NN*64] | s1[NN] | s2[NN] | bcur[NB] | recs u64[NB*RCAP]
    char* p = (char*)d_ws;
    int*                flags  = (int*)p;            p += 256;
    unsigned short*     Wt     = (unsigned short*)p; p += ((size_t)FOUT * FIN * 2 + 255) / 256 * 256;
    unsigned short*     h      = (unsigned short*)p; p += ((size_t)NN * FOUT * 2 + 255) / 256 * 256;
    float*              s1     = (float*)p;          p += ((size_t)NN * 4 + 255) / 256 * 256;
    float*              s2     = (float*)p;          p += ((size_t)NN * 4 + 255) / 256 * 256;
    int*                bcur   = (int*)p;            p += ((size_t)NB * 4 + 255) / 256 * 256;
    unsigned long long* recs   = (unsigned long long*)p;

    detwt_kernel<<<32, 256, 0, stream>>>(W, Mv, Wt, flags, bcur);
    mfma_gemm_kernel<<<(NN + 31) / 32, 256, 0, stream>>>(inp, Wt, a, h, s1, s2, flags);
    partition_kernel<<<PGRID, 1024, 0, stream>>>(edge, Mv, flags, s1, s2, bcur, recs);
    csr_spmm_kernel<<<NB, 512, 0, stream>>>(bcur, recs, h, flags, d_out);
}